// Round 1
// baseline (3408.229 us; speedup 1.0000x reference)
//
#include <hip/hip_runtime.h>

// ---------------------------------------------------------------------------
// Qwen3-style 8-layer transformer forward on MI355X (gfx950).
// Residual stream f32; all matmuls bf16 MFMA (16x16x32), m97-style GEMM:
// 128x128 tile, BK=32, 4 waves, global_load_lds(16B) staging.
// ---------------------------------------------------------------------------

typedef unsigned short u16;                                   // bf16 storage
typedef __bf16 bf16x8 __attribute__((ext_vector_type(8)));    // MFMA A/B frag
typedef float  f32x4  __attribute__((ext_vector_type(4)));    // MFMA C/D frag

#define DEV static __device__ __forceinline__

constexpr int NB  = 2;
constexpr int S   = 1024;
constexpr int NT  = NB * S;      // 2048 tokens
constexpr int H   = 1024;
constexpr int NH  = 16;
constexpr int NKV = 8;
constexpr int HD  = 64;
constexpr int NL  = 8;
constexpr int FF  = 4096;
constexpr int V   = 32000;

DEV float b2f(u16 x) { return __uint_as_float(((unsigned)x) << 16); }
DEV u16   f2b(float f) {
  unsigned i = __float_as_uint(f);
  return (u16)((i + 0x7fffu + ((i >> 16) & 1u)) >> 16);   // RNE
}

DEV void gload16(const void* g, void* l) {
  __builtin_amdgcn_global_load_lds(
      (const __attribute__((address_space(1))) void*)g,
      (__attribute__((address_space(3))) void*)l, 16, 0, 0);
}

// ---------------------------------------------------------------------------
// GEMM: C[M,N] = A[M,K](bf16) * B[K,N], with B given transposed: Bt[N][K] bf16.
// EPI: 0 = write bf16; 1 = f32 residual add (C += acc); 2 = silu(aux)*acc -> bf16;
//      3 = write f32.
// BMODE: 0 none; 1 attention scores (z = b*16+h); 2 attention PV.
// ---------------------------------------------------------------------------
template <int BM, int BN, int WM, int WN, int EPI, int BMODE>
__global__ __launch_bounds__(256) void gemm_k(
    const u16* __restrict__ A, int lda,
    const u16* __restrict__ Bt, int ldb,
    void* __restrict__ C, int ldc,
    const void* __restrict__ aux, int K)
{
  __shared__ __align__(16) u16 As[BM * 32];
  __shared__ __align__(16) u16 Bs[BN * 32];

  const int tid  = threadIdx.x;
  const int lane = tid & 63;
  const int lrow = lane & 15;
  const int kb   = lane >> 4;
  const int w    = tid >> 6;
  const int wm   = w / WN, wn = w % WN;
  constexpr int WR = BM / WM, WC = BN / WN;
  constexpr int FM = WR / 16, FN = WC / 16;

  int aOff = 0, bOff = 0, cOff = 0;
  if (BMODE == 1) {
    const int z = blockIdx.z, b = z >> 4, hh = z & 15;
    aOff = b * S * lda + hh * HD;
    bOff = b * S * ldb + (hh >> 1) * HD;
    cOff = z * S * S;
  } else if (BMODE == 2) {
    const int z = blockIdx.z, b = z >> 4, hh = z & 15;
    aOff = z * S * S;
    bOff = (b * NKV + (hh >> 1)) * HD * S;
    cOff = b * S * ldc + hh * HD;
  }

  const u16* Ap = A + aOff + blockIdx.x * BM * lda;
  const u16* Bp = Bt + bOff + blockIdx.y * BN * ldb;

  f32x4 acc[FM][FN] = {};

  for (int k0 = 0; k0 < K; k0 += 32) {
    #pragma unroll
    for (int i = 0; i < (BM * 4) / 256; i++) {
      const int c = i * 256 + tid;
      gload16(Ap + (c >> 2) * lda + k0 + (c & 3) * 8, (char*)As + c * 16);
    }
    #pragma unroll
    for (int i = 0; i < (BN * 4) / 256; i++) {
      const int c = i * 256 + tid;
      gload16(Bp + (c >> 2) * ldb + k0 + (c & 3) * 8, (char*)Bs + c * 16);
    }
    __syncthreads();

    bf16x8 af[FM], bfv[FN];
    #pragma unroll
    for (int fm = 0; fm < FM; fm++)
      af[fm] = *reinterpret_cast<const bf16x8*>(As + (wm * WR + fm * 16 + lrow) * 32 + kb * 8);
    #pragma unroll
    for (int fn = 0; fn < FN; fn++)
      bfv[fn] = *reinterpret_cast<const bf16x8*>(Bs + (wn * WC + fn * 16 + lrow) * 32 + kb * 8);

    #pragma unroll
    for (int fm = 0; fm < FM; fm++) {
      #pragma unroll
      for (int fn = 0; fn < FN; fn++) {
        acc[fm][fn] = __builtin_amdgcn_mfma_f32_16x16x32_bf16(af[fm], bfv[fn], acc[fm][fn], 0, 0, 0);
      }
    }
    __syncthreads();
  }

  #pragma unroll
  for (int fm = 0; fm < FM; fm++) {
    #pragma unroll
    for (int fn = 0; fn < FN; fn++) {
      #pragma unroll
      for (int r = 0; r < 4; r++) {
        const int row = blockIdx.x * BM + wm * WR + fm * 16 + kb * 4 + r;
        const int col = blockIdx.y * BN + wn * WC + fn * 16 + lrow;
        const float vv = acc[fm][fn][r];
        if (EPI == 0) {
          ((u16*)C)[cOff + row * ldc + col] = f2b(vv);
        } else if (EPI == 1) {
          ((float*)C)[row * ldc + col] += vv;
        } else if (EPI == 2) {
          const float g  = b2f(((const u16*)aux)[row * ldc + col]);
          const float sg = g / (1.f + __expf(-g));
          ((u16*)C)[row * ldc + col] = f2b(sg * vv);
        } else {
          ((float*)C)[cOff + row * ldc + col] = vv;
        }
      }
    }
  }
}

// ---------------------------------------------------------------------------
// Transpose-convert: W[K][N] f32  ->  WT[N][K] bf16   (32x32 tiles, 256 thr)
// ---------------------------------------------------------------------------
__global__ __launch_bounds__(256) void transpose_k(
    const float* __restrict__ W, u16* __restrict__ WT, int K, int N)
{
  __shared__ float t[32][33];
  const int k0 = blockIdx.x * 32, n0 = blockIdx.y * 32;
  const int tx = threadIdx.x & 31, ty = threadIdx.x >> 5;
  #pragma unroll
  for (int i = 0; i < 32; i += 8)
    t[ty + i][tx] = W[(k0 + ty + i) * N + (n0 + tx)];
  __syncthreads();
  #pragma unroll
  for (int i = 0; i < 32; i += 8)
    WT[(n0 + ty + i) * K + (k0 + tx)] = f2b(t[tx][ty + i]);
}

// v[NT][NKV*HD] bf16 -> vT[b][kh][HD][S] bf16
__global__ __launch_bounds__(256) void transpose_v_k(
    const u16* __restrict__ v, u16* __restrict__ vT)
{
  __shared__ float t[32][33];
  const int s0 = blockIdx.x * 32, d0 = blockIdx.y * 32;
  const int bh = blockIdx.z, b = bh >> 3, kh = bh & 7;
  const int tx = threadIdx.x & 31, ty = threadIdx.x >> 5;
  #pragma unroll
  for (int i = 0; i < 32; i += 8)
    t[ty + i][tx] = b2f(v[(b * S + s0 + ty + i) * (NKV * HD) + kh * HD + d0 + tx]);
  __syncthreads();
  #pragma unroll
  for (int i = 0; i < 32; i += 8)
    vT[((b * NKV + kh) * HD + d0 + ty + i) * S + (s0 + tx)] = f2b(t[tx][ty + i]);
}

// ---------------------------------------------------------------------------
// Embedding gather (f32)
// ---------------------------------------------------------------------------
__global__ __launch_bounds__(256) void embed_k(
    const int* __restrict__ ids, const float* __restrict__ E, float* __restrict__ h)
{
  const int t = blockIdx.x;
  const int id = ids[t];
  ((float4*)(h + t * H))[threadIdx.x] = ((const float4*)(E + (size_t)id * H))[threadIdx.x];
}

// ---------------------------------------------------------------------------
// RMSNorm: f32 in -> bf16 out  (one block per row, 256 thr x float4)
// ---------------------------------------------------------------------------
__global__ __launch_bounds__(256) void rmsnorm_k(
    const float* __restrict__ h, const float* __restrict__ w, u16* __restrict__ x)
{
  const int row = blockIdx.x;
  const float4 hv = ((const float4*)(h + row * H))[threadIdx.x];
  float s = hv.x * hv.x + hv.y * hv.y + hv.z * hv.z + hv.w * hv.w;
  #pragma unroll
  for (int off = 32; off; off >>= 1) s += __shfl_xor(s, off, 64);
  __shared__ float red[4];
  if ((threadIdx.x & 63) == 0) red[threadIdx.x >> 6] = s;
  __syncthreads();
  s = red[0] + red[1] + red[2] + red[3];
  const float scale = rsqrtf(s * (1.f / H) + 1e-6f);
  const float4 wv = ((const float4*)w)[threadIdx.x];
  ushort4 ov;
  ov.x = f2b(hv.x * scale * wv.x);
  ov.y = f2b(hv.y * scale * wv.y);
  ov.z = f2b(hv.z * scale * wv.z);
  ov.w = f2b(hv.w * scale * wv.w);
  ((ushort4*)(x + row * H))[threadIdx.x] = ov;
}

// ---------------------------------------------------------------------------
// RoPE in place on [NT][nh*HD] bf16; one thread per (token, head, pair).
// scale folds 1/sqrt(HD) into q.
// ---------------------------------------------------------------------------
__global__ __launch_bounds__(256) void rope_k(u16* __restrict__ buf, int nh, float scale)
{
  const int idx = blockIdx.x * 256 + threadIdx.x;
  const int d = idx & 31;
  const int rest = idx >> 5;
  const int hh = rest % nh;
  const int t = rest / nh;
  const int s = t & (S - 1);
  const float ang = s * powf(10000.f, -(2.f * d) / 64.f);
  float sn, cs;
  sincosf(ang, &sn, &cs);
  u16* p = buf + (t * nh + hh) * HD + d;
  const float x1 = b2f(p[0]), x2 = b2f(p[32]);
  p[0]  = f2b((x1 * cs - x2 * sn) * scale);
  p[32] = f2b((x2 * cs + x1 * sn) * scale);
}

// ---------------------------------------------------------------------------
// Causal softmax in place on scores bf16 [32][S][S]; block = one row.
// ---------------------------------------------------------------------------
__global__ __launch_bounds__(256) void softmax_k(u16* __restrict__ sc)
{
  const int r = blockIdx.x, z = blockIdx.y;
  u16* row = sc + ((size_t)z * S + r) * S;
  const int tid = threadIdx.x;
  const ushort4 raw = ((const ushort4*)row)[tid];
  float vv[4] = { b2f(raw.x), b2f(raw.y), b2f(raw.z), b2f(raw.w) };
  const int c0 = tid * 4;
  float m = -1e30f;
  #pragma unroll
  for (int j = 0; j < 4; j++) {
    if (c0 + j <= r) m = fmaxf(m, vv[j]); else vv[j] = -1e30f;
  }
  #pragma unroll
  for (int off = 32; off; off >>= 1) m = fmaxf(m, __shfl_xor(m, off, 64));
  __shared__ float redm[4], reds[4];
  if ((tid & 63) == 0) redm[tid >> 6] = m;
  __syncthreads();
  m = fmaxf(fmaxf(redm[0], redm[1]), fmaxf(redm[2], redm[3]));
  float e[4], sum = 0.f;
  #pragma unroll
  for (int j = 0; j < 4; j++) {
    e[j] = (c0 + j <= r) ? __expf(vv[j] - m) : 0.f;
    sum += e[j];
  }
  #pragma unroll
  for (int off = 32; off; off >>= 1) sum += __shfl_xor(sum, off, 64);
  if ((tid & 63) == 0) reds[tid >> 6] = sum;
  __syncthreads();
  sum = reds[0] + reds[1] + reds[2] + reds[3];
  const float inv = 1.f / sum;
  ushort4 ov;
  ov.x = f2b(e[0] * inv);
  ov.y = f2b(e[1] * inv);
  ov.z = f2b(e[2] * inv);
  ov.w = f2b(e[3] * inv);
  ((ushort4*)row)[tid] = ov;
}

// ---------------------------------------------------------------------------
extern "C" void kernel_launch(void* const* d_in, const int* in_sizes, int n_in,
                              void* d_out, int out_size, void* d_ws, size_t ws_size,
                              hipStream_t stream)
{
  const int*   ids  = (const int*)d_in[0];
  const float* EW   = (const float*)d_in[1];
  const float* Wq   = (const float*)d_in[2];
  const float* Wk   = (const float*)d_in[3];
  const float* Wv   = (const float*)d_in[4];
  const float* Wo   = (const float*)d_in[5];
  const float* Wg   = (const float*)d_in[6];
  const float* Wu   = (const float*)d_in[7];
  const float* Wd   = (const float*)d_in[8];
  const float* ln1  = (const float*)d_in[9];
  const float* ln2  = (const float*)d_in[10];
  const float* nw   = (const float*)d_in[11];
  const float* lmw  = (const float*)d_in[12];
  float* out = (float*)d_out;

  char* ws = (char*)d_ws;
  float* h   = (float*)(ws);                      // 8 MiB   [NT][H] f32
  u16*   x   = (u16*)(ws + (8u  << 20));          // 4 MiB   [NT][H]
  u16*   q   = (u16*)(ws + (12u << 20));          // 4 MiB   [NT][NH*HD]
  u16*   kB  = (u16*)(ws + (16u << 20));          // 2 MiB   [NT][NKV*HD]
  u16*   vB  = (u16*)(ws + (18u << 20));          // 2 MiB   [NT][NKV*HD]
  u16*   vT  = (u16*)(ws + (20u << 20));          // 2 MiB   [NB][NKV][HD][S]
  u16*   o   = (u16*)(ws + (22u << 20));          // 4 MiB   [NT][NH*HD]
  u16*   gb  = (u16*)(ws + (26u << 20));          // 16 MiB  [NT][FF]
  u16*   ub  = (u16*)(ws + (42u << 20));          // 16 MiB  [NT][FF]
  u16*   sc  = (u16*)(ws + (58u << 20));          // 64 MiB  [32][S][S]
  u16*   WT  = (u16*)(ws + (122u << 20));         // 62.5 MiB (max: lm_head)

  const size_t needed = (122u << 20) + (size_t)V * H * 2;
  if (ws_size < needed) return;   // not enough scratch; fail loudly via absmax

  embed_k<<<NT, 256, 0, stream>>>(ids, EW, h);

  for (int l = 0; l < NL; l++) {
    // ---- attention ----
    rmsnorm_k<<<NT, 256, 0, stream>>>(h, ln1 + l * H, x);

    transpose_k<<<dim3(H / 32, H / 32), 256, 0, stream>>>(Wq + (size_t)l * H * H, WT, H, H);
    gemm_k<128, 128, 2, 2, 0, 0><<<dim3(NT / 128, H / 128), 256, 0, stream>>>(
        x, H, WT, H, q, H, nullptr, H);

    transpose_k<<<dim3(H / 32, (NKV * HD) / 32), 256, 0, stream>>>(Wk + (size_t)l * H * NKV * HD, WT, H, NKV * HD);
    gemm_k<128, 128, 2, 2, 0, 0><<<dim3(NT / 128, (NKV * HD) / 128), 256, 0, stream>>>(
        x, H, WT, H, kB, NKV * HD, nullptr, H);

    transpose_k<<<dim3(H / 32, (NKV * HD) / 32), 256, 0, stream>>>(Wv + (size_t)l * H * NKV * HD, WT, H, NKV * HD);
    gemm_k<128, 128, 2, 2, 0, 0><<<dim3(NT / 128, (NKV * HD) / 128), 256, 0, stream>>>(
        x, H, WT, H, vB, NKV * HD, nullptr, H);

    rope_k<<<(NT * NH * 32) / 256, 256, 0, stream>>>(q, NH, 0.125f);
    rope_k<<<(NT * NKV * 32) / 256, 256, 0, stream>>>(kB, NKV, 1.0f);

    transpose_v_k<<<dim3(S / 32, HD / 32, NB * NKV), 256, 0, stream>>>(vB, vT);

    // scores[z][sq][sk] = q . k  (scale already folded into q)
    gemm_k<128, 128, 2, 2, 0, 1><<<dim3(S / 128, S / 128, NB * NH), 256, 0, stream>>>(
        q, H, kB, NKV * HD, sc, S, nullptr, HD);

    softmax_k<<<dim3(S, NB * NH), 256, 0, stream>>>(sc);

    // o[z] = probs @ v
    gemm_k<128, 64, 4, 1, 0, 2><<<dim3(S / 128, 1, NB * NH), 256, 0, stream>>>(
        sc, S, vT, S, o, H, nullptr, S);

    transpose_k<<<dim3(H / 32, H / 32), 256, 0, stream>>>(Wo + (size_t)l * H * H, WT, H, H);
    gemm_k<128, 128, 2, 2, 1, 0><<<dim3(NT / 128, H / 128), 256, 0, stream>>>(
        o, H, WT, H, h, H, nullptr, H);

    // ---- MLP ----
    rmsnorm_k<<<NT, 256, 0, stream>>>(h, ln2 + l * H, x);

    transpose_k<<<dim3(H / 32, FF / 32), 256, 0, stream>>>(Wg + (size_t)l * H * FF, WT, H, FF);
    gemm_k<128, 128, 2, 2, 0, 0><<<dim3(NT / 128, FF / 128), 256, 0, stream>>>(
        x, H, WT, H, gb, FF, nullptr, H);

    transpose_k<<<dim3(H / 32, FF / 32), 256, 0, stream>>>(Wu + (size_t)l * H * FF, WT, H, FF);
    gemm_k<128, 128, 2, 2, 2, 0><<<dim3(NT / 128, FF / 128), 256, 0, stream>>>(
        x, H, WT, H, ub, FF, gb, H);

    transpose_k<<<dim3(FF / 32, H / 32), 256, 0, stream>>>(Wd + (size_t)l * FF * H, WT, FF, H);
    gemm_k<128, 128, 2, 2, 1, 0><<<dim3(NT / 128, H / 128), 256, 0, stream>>>(
        ub, FF, WT, FF, h, H, nullptr, FF);
  }

  rmsnorm_k<<<NT, 256, 0, stream>>>(h, nw, x);
  transpose_k<<<dim3(H / 32, V / 32), 256, 0, stream>>>(lmw, WT, H, V);
  gemm_k<128, 128, 2, 2, 3, 0><<<dim3(NT / 128, V / 128), 256, 0, stream>>>(
      x, H, WT, H, out, V, nullptr, H);
}

// Round 2
// 2747.838 us; speedup vs baseline: 1.2403x; 1.2403x over previous
//
#include <hip/hip_runtime.h>

// ---------------------------------------------------------------------------
// Qwen3-style 8-layer transformer forward on MI355X (gfx950).
// Round 2: fused flash attention, fused QKV GEMM, table-based RoPE.
// ---------------------------------------------------------------------------

typedef unsigned short u16;
typedef __bf16  bf16x8 __attribute__((ext_vector_type(8)));   // 4 VGPRs
typedef unsigned short u16x8 __attribute__((ext_vector_type(8)));
typedef float   f32x4  __attribute__((ext_vector_type(4)));

#define DEV static __device__ __forceinline__

constexpr int NB  = 2;
constexpr int S   = 1024;
constexpr int NT  = NB * S;
constexpr int H   = 1024;
constexpr int NH  = 16;
constexpr int NKV = 8;
constexpr int HD  = 64;
constexpr int NL  = 8;
constexpr int FF  = 4096;
constexpr int V   = 32000;
constexpr int QKVW = 2048;       // fused qkv row width

DEV float b2f(u16 x) { return __uint_as_float(((unsigned)x) << 16); }
DEV u16   f2b(float f) {
  unsigned i = __float_as_uint(f);
  return (u16)((i + 0x7fffu + ((i >> 16) & 1u)) >> 16);   // RNE
}

DEV void gload16(const void* g, void* l) {
  __builtin_amdgcn_global_load_lds(
      (const __attribute__((address_space(1))) void*)g,
      (__attribute__((address_space(3))) void*)l, 16, 0, 0);
}

// ---------------------------------------------------------------------------
// GEMM: C[M,N] = A[M,K](bf16) * Bt[N][K](bf16).
// EPI: 0 = bf16 out; 1 = f32 residual add; 2 = silu(aux)*acc -> bf16; 3 = f32 out.
// ---------------------------------------------------------------------------
template <int BM, int BN, int WM, int WN, int EPI>
__global__ __launch_bounds__(256) void gemm_k(
    const u16* __restrict__ A, int lda,
    const u16* __restrict__ Bt, int ldb,
    void* __restrict__ C, int ldc,
    const void* __restrict__ aux, int K)
{
  __shared__ __align__(16) u16 As[BM * 32];
  __shared__ __align__(16) u16 Bs[BN * 32];

  const int tid  = threadIdx.x;
  const int lane = tid & 63;
  const int lrow = lane & 15;
  const int kb   = lane >> 4;
  const int w    = tid >> 6;
  const int wm   = w / WN, wn = w % WN;
  constexpr int WR = BM / WM, WC = BN / WN;
  constexpr int FM = WR / 16, FN = WC / 16;

  const u16* Ap = A + blockIdx.x * BM * lda;
  const u16* Bp = Bt + blockIdx.y * BN * ldb;

  f32x4 acc[FM][FN] = {};

  for (int k0 = 0; k0 < K; k0 += 32) {
    #pragma unroll
    for (int i = 0; i < (BM * 4) / 256; i++) {
      const int c = i * 256 + tid;
      gload16(Ap + (c >> 2) * lda + k0 + (c & 3) * 8, (char*)As + c * 16);
    }
    #pragma unroll
    for (int i = 0; i < (BN * 4) / 256; i++) {
      const int c = i * 256 + tid;
      gload16(Bp + (c >> 2) * ldb + k0 + (c & 3) * 8, (char*)Bs + c * 16);
    }
    __syncthreads();

    bf16x8 af[FM], bfv[FN];
    #pragma unroll
    for (int fm = 0; fm < FM; fm++)
      af[fm] = *reinterpret_cast<const bf16x8*>(As + (wm * WR + fm * 16 + lrow) * 32 + kb * 8);
    #pragma unroll
    for (int fn = 0; fn < FN; fn++)
      bfv[fn] = *reinterpret_cast<const bf16x8*>(Bs + (wn * WC + fn * 16 + lrow) * 32 + kb * 8);

    #pragma unroll
    for (int fm = 0; fm < FM; fm++) {
      #pragma unroll
      for (int fn = 0; fn < FN; fn++) {
        acc[fm][fn] = __builtin_amdgcn_mfma_f32_16x16x32_bf16(af[fm], bfv[fn], acc[fm][fn], 0, 0, 0);
      }
    }
    __syncthreads();
  }

  #pragma unroll
  for (int fm = 0; fm < FM; fm++) {
    #pragma unroll
    for (int fn = 0; fn < FN; fn++) {
      #pragma unroll
      for (int r = 0; r < 4; r++) {
        const int row = blockIdx.x * BM + wm * WR + fm * 16 + kb * 4 + r;
        const int col = blockIdx.y * BN + wn * WC + fn * 16 + lrow;
        const float vv = acc[fm][fn][r];
        if (EPI == 0) {
          ((u16*)C)[row * ldc + col] = f2b(vv);
        } else if (EPI == 1) {
          ((float*)C)[row * ldc + col] += vv;
        } else if (EPI == 2) {
          const float g  = b2f(((const u16*)aux)[row * ldc + col]);
          const float sg = g / (1.f + __expf(-g));
          ((u16*)C)[row * ldc + col] = f2b(sg * vv);
        } else {
          ((float*)C)[(size_t)row * ldc + col] = vv;
        }
      }
    }
  }
}

// ---------------------------------------------------------------------------
// Transpose-convert: W[K][N] f32 -> WT[N][K] bf16
// ---------------------------------------------------------------------------
__global__ __launch_bounds__(256) void transpose_k(
    const float* __restrict__ W, u16* __restrict__ WT, int K, int N)
{
  __shared__ float t[32][33];
  const int k0 = blockIdx.x * 32, n0 = blockIdx.y * 32;
  const int tx = threadIdx.x & 31, ty = threadIdx.x >> 5;
  #pragma unroll
  for (int i = 0; i < 32; i += 8)
    t[ty + i][tx] = W[(k0 + ty + i) * N + (n0 + tx)];
  __syncthreads();
  #pragma unroll
  for (int i = 0; i < 32; i += 8)
    WT[(n0 + ty + i) * K + (k0 + tx)] = f2b(t[tx][ty + i]);
}

// ---------------------------------------------------------------------------
__global__ __launch_bounds__(256) void embed_k(
    const int* __restrict__ ids, const float* __restrict__ E, float* __restrict__ h)
{
  const int t = blockIdx.x;
  const int id = ids[t];
  ((float4*)(h + t * H))[threadIdx.x] = ((const float4*)(E + (size_t)id * H))[threadIdx.x];
}

// ---------------------------------------------------------------------------
__global__ __launch_bounds__(256) void rmsnorm_k(
    const float* __restrict__ h, const float* __restrict__ w, u16* __restrict__ x)
{
  const int row = blockIdx.x;
  const float4 hv = ((const float4*)(h + row * H))[threadIdx.x];
  float s = hv.x * hv.x + hv.y * hv.y + hv.z * hv.z + hv.w * hv.w;
  #pragma unroll
  for (int off = 32; off; off >>= 1) s += __shfl_xor(s, off, 64);
  __shared__ float red[4];
  if ((threadIdx.x & 63) == 0) red[threadIdx.x >> 6] = s;
  __syncthreads();
  s = red[0] + red[1] + red[2] + red[3];
  const float scale = rsqrtf(s * (1.f / H) + 1e-6f);
  const float4 wv = ((const float4*)w)[threadIdx.x];
  ushort4 ov;
  ov.x = f2b(hv.x * scale * wv.x);
  ov.y = f2b(hv.y * scale * wv.y);
  ov.z = f2b(hv.z * scale * wv.z);
  ov.w = f2b(hv.w * scale * wv.w);
  ((ushort4*)(x + row * H))[threadIdx.x] = ov;
}

// ---------------------------------------------------------------------------
// RoPE tables: tab[s][d] = (cos, sin)  d = 0..31
// ---------------------------------------------------------------------------
__global__ __launch_bounds__(256) void ropetab_k(float2* __restrict__ tab)
{
  const int idx = blockIdx.x * 256 + threadIdx.x;   // S*32 threads
  const int s = idx >> 5, d = idx & 31;
  const float ang = s * powf(10000.f, -(2.f * d) / 64.f);
  float sn, cs;
  sincosf(ang, &sn, &cs);
  tab[idx] = make_float2(cs, sn);
}

// RoPE in place on qkv [NT][2048]; q heads scaled by 1/sqrt(HD).
__global__ __launch_bounds__(256) void rope_k(
    u16* __restrict__ qkv, const float2* __restrict__ tab)
{
  const int idx = blockIdx.x * 256 + threadIdx.x;   // NT*24*32
  const int d = idx & 31;
  const int rest = idx >> 5;
  const int hh = rest % 24;
  const int t = rest / 24;
  const int s = t & (S - 1);
  const float2 cssn = tab[s * 32 + d];
  const float scale = (hh < 16) ? 0.125f : 1.0f;
  const int col = (hh < 16) ? hh * 64 : 1024 + (hh - 16) * 64;
  u16* p = qkv + (size_t)t * QKVW + col + d;
  const float x1 = b2f(p[0]), x2 = b2f(p[32]);
  p[0]  = f2b((x1 * cssn.x - x2 * cssn.y) * scale);
  p[32] = f2b((x2 * cssn.x + x1 * cssn.y) * scale);
}

// ---------------------------------------------------------------------------
// Flash attention.  grid(16, 32): bx = q-tile of 64 rows, by = b*16+h.
// 256 thr = 4 waves, each wave owns 16 q-rows.  KV tiles of 64.
// qkv layout per token row (2048): [q 16*64 | k 8*64 | v 8*64], q pre-scaled.
// ---------------------------------------------------------------------------
__global__ __launch_bounds__(256) void fattn_k(
    const u16* __restrict__ qkv, u16* __restrict__ o)
{
  __shared__ __align__(16) u16 Ks[64 * 64];       // [k][d], chunk-XOR swizzled
  __shared__ __align__(16) u16 Vt[64 * 72];       // [d][k], pad 72 + chunk swz
  __shared__ __align__(16) u16 Pw[4][16 * 64];    // per-wave P, chunk swz

  const int tid  = threadIdx.x;
  const int lane = tid & 63;
  const int lrow = lane & 15;
  const int g    = lane >> 4;
  const int w    = tid >> 6;
  const int bx = blockIdx.x, by = blockIdx.y;
  const int b = by >> 4, hh = by & 15, kh = hh >> 1;
  const int q0 = bx * 64;

  // Q fragments (A-layout: lane&15 = q-row, regs = d)
  bf16x8 aq[2];
  {
    const int qrow = q0 + w * 16 + lrow;
    const u16* qp = qkv + (size_t)(b * S + qrow) * QKVW + hh * 64 + g * 8;
    aq[0] = *reinterpret_cast<const bf16x8*>(qp);
    aq[1] = *reinterpret_cast<const bf16x8*>(qp + 32);
  }

  f32x4 oacc[4] = {};
  float mrow[4], lsum[4];
  #pragma unroll
  for (int r = 0; r < 4; r++) { mrow[r] = -1e30f; lsum[r] = 0.f; }

  const int nt = bx + 1;
  for (int t = 0; t < nt; t++) {
    const int kv0 = t * 64;
    __syncthreads();   // prev iteration's Ks/Vt reads done

    // stage K tile [64][64] via global_load_lds, source pre-swizzled
    #pragma unroll
    for (int i = 0; i < 2; i++) {
      const int c = i * 256 + tid;
      const int r = c >> 3, p = c & 7;
      gload16(qkv + (size_t)(b * S + kv0 + r) * QKVW + 1024 + kh * 64 + ((p ^ (r & 7)) * 8),
              (char*)Ks + c * 16);
    }
    // stage V tile to regs (coalesced), then transposed LDS write
    u16x8 vreg[2];
    #pragma unroll
    for (int i = 0; i < 2; i++) {
      const int c = i * 256 + tid;
      const int k = c >> 3, dch = c & 7;
      vreg[i] = *reinterpret_cast<const u16x8*>(
          qkv + (size_t)(b * S + kv0 + k) * QKVW + 1536 + kh * 64 + dch * 8);
    }
    #pragma unroll
    for (int i = 0; i < 2; i++) {
      const int c = i * 256 + tid;
      const int k = c >> 3, d0 = (c & 7) * 8;
      #pragma unroll
      for (int j = 0; j < 8; j++) {
        const int d = d0 + j;
        Vt[d * 72 + (((k >> 3) ^ (d >> 3)) * 8) + (k & 7)] = vreg[i][j];
      }
    }
    __syncthreads();   // K staged (vmcnt) + Vt written

    // QK^T -> sacc[n] (C-layout: q-local = g*4+r, k-local = lane&15)
    f32x4 sacc[4] = {};
    #pragma unroll
    for (int n = 0; n < 4; n++) {
      const int row = n * 16 + lrow;
      #pragma unroll
      for (int k2 = 0; k2 < 2; k2++) {
        const bf16x8 bk = *reinterpret_cast<const bf16x8*>(
            Ks + row * 64 + (((k2 * 4 + g) ^ (row & 7)) * 8));
        sacc[n] = __builtin_amdgcn_mfma_f32_16x16x32_bf16(aq[k2], bk, sacc[n], 0, 0, 0);
      }
    }

    // online softmax + P -> LDS
    #pragma unroll
    for (int r = 0; r < 4; r++) {
      const int qglob = q0 + w * 16 + g * 4 + r;
      float sv[4];
      float rm = -1e30f;
      #pragma unroll
      for (int n = 0; n < 4; n++) {
        const int kg = kv0 + n * 16 + lrow;
        sv[n] = (kg <= qglob) ? sacc[n][r] : -1e30f;
        rm = fmaxf(rm, sv[n]);
      }
      #pragma unroll
      for (int mk = 1; mk < 16; mk <<= 1) rm = fmaxf(rm, __shfl_xor(rm, mk, 64));
      const float mnew  = fmaxf(mrow[r], rm);
      const float scale = __expf(mrow[r] - mnew);
      float rs = 0.f;
      u16 pb[4];
      #pragma unroll
      for (int n = 0; n < 4; n++) {
        const float p = __expf(sv[n] - mnew);
        rs += p;
        pb[n] = f2b(p);
      }
      #pragma unroll
      for (int mk = 1; mk < 16; mk <<= 1) rs += __shfl_xor(rs, mk, 64);
      lsum[r] = lsum[r] * scale + rs;
      mrow[r] = mnew;
      #pragma unroll
      for (int dt = 0; dt < 4; dt++) oacc[dt][r] *= scale;
      const int ql = g * 4 + r;
      #pragma unroll
      for (int n = 0; n < 4; n++) {
        const int k = n * 16 + lrow;
        Pw[w][ql * 64 + (((k >> 3) ^ (ql & 7)) * 8) + (k & 7)] = pb[n];
      }
    }

    // PV: oacc[dt] += P[q][k] * V[k][d]
    #pragma unroll
    for (int k2 = 0; k2 < 2; k2++) {
      const bf16x8 pa = *reinterpret_cast<const bf16x8*>(
          &Pw[w][lrow * 64 + (((k2 * 4 + g) ^ (lrow & 7)) * 8)]);
      #pragma unroll
      for (int dt = 0; dt < 4; dt++) {
        const int d = dt * 16 + lrow;
        const bf16x8 vb = *reinterpret_cast<const bf16x8*>(
            &Vt[d * 72 + (((k2 * 4 + g) ^ (d >> 3)) * 8)]);
        oacc[dt] = __builtin_amdgcn_mfma_f32_16x16x32_bf16(pa, vb, oacc[dt], 0, 0, 0);
      }
    }
  }

  // epilogue: O = oacc / l
  #pragma unroll
  for (int dt = 0; dt < 4; dt++) {
    #pragma unroll
    for (int r = 0; r < 4; r++) {
      const int qrow = q0 + w * 16 + g * 4 + r;
      o[(size_t)(b * S + qrow) * H + hh * 64 + dt * 16 + lrow] =
          f2b(oacc[dt][r] / lsum[r]);
    }
  }
}

// ---------------------------------------------------------------------------
extern "C" void kernel_launch(void* const* d_in, const int* in_sizes, int n_in,
                              void* d_out, int out_size, void* d_ws, size_t ws_size,
                              hipStream_t stream)
{
  const int*   ids  = (const int*)d_in[0];
  const float* EW   = (const float*)d_in[1];
  const float* Wq   = (const float*)d_in[2];
  const float* Wk   = (const float*)d_in[3];
  const float* Wv   = (const float*)d_in[4];
  const float* Wo   = (const float*)d_in[5];
  const float* Wg   = (const float*)d_in[6];
  const float* Wu   = (const float*)d_in[7];
  const float* Wd   = (const float*)d_in[8];
  const float* ln1  = (const float*)d_in[9];
  const float* ln2  = (const float*)d_in[10];
  const float* nw   = (const float*)d_in[11];
  const float* lmw  = (const float*)d_in[12];
  float* out = (float*)d_out;

  char* ws = (char*)d_ws;
  float*  h   = (float*)(ws);                     // 8 MiB  [NT][H] f32
  u16*    x   = (u16*)(ws + (8u  << 20));         // 4 MiB  [NT][H]
  u16*    qkv = (u16*)(ws + (12u << 20));         // 8 MiB  [NT][2048]
  u16*    o   = (u16*)(ws + (20u << 20));         // 4 MiB  [NT][H]
  u16*    gb  = (u16*)(ws + (24u << 20));         // 16 MiB [NT][FF]
  u16*    ub  = (u16*)(ws + (40u << 20));         // 16 MiB [NT][FF]
  u16*    WT  = (u16*)(ws + (56u << 20));         // 62.5 MiB (max lm_head)
  float2* tab = (float2*)(ws + (120u << 20));     // 256 KiB [S][32]

  const size_t needed = (120u << 20) + (size_t)S * 32 * sizeof(float2);
  if (ws_size < needed) return;

  embed_k<<<NT, 256, 0, stream>>>(ids, EW, h);
  ropetab_k<<<(S * 32) / 256, 256, 0, stream>>>(tab);

  for (int l = 0; l < NL; l++) {
    // ---- attention ----
    rmsnorm_k<<<NT, 256, 0, stream>>>(h, ln1 + l * H, x);

    transpose_k<<<dim3(H / 32, H / 32), 256, 0, stream>>>(Wq + (size_t)l * H * H, WT, H, H);
    transpose_k<<<dim3(H / 32, 512 / 32), 256, 0, stream>>>(Wk + (size_t)l * H * 512, WT + 1024 * H, H, 512);
    transpose_k<<<dim3(H / 32, 512 / 32), 256, 0, stream>>>(Wv + (size_t)l * H * 512, WT + 1536 * H, H, 512);
    gemm_k<128, 128, 2, 2, 0><<<dim3(NT / 128, QKVW / 128), 256, 0, stream>>>(
        x, H, WT, H, qkv, QKVW, nullptr, H);

    rope_k<<<(NT * 24 * 32) / 256, 256, 0, stream>>>(qkv, tab);

    fattn_k<<<dim3(S / 64, NB * NH), 256, 0, stream>>>(qkv, o);

    transpose_k<<<dim3(H / 32, H / 32), 256, 0, stream>>>(Wo + (size_t)l * H * H, WT, H, H);
    gemm_k<128, 128, 2, 2, 1><<<dim3(NT / 128, H / 128), 256, 0, stream>>>(
        o, H, WT, H, h, H, nullptr, H);

    // ---- MLP ----
    rmsnorm_k<<<NT, 256, 0, stream>>>(h, ln2 + l * H, x);

    transpose_k<<<dim3(H / 32, FF / 32), 256, 0, stream>>>(Wg + (size_t)l * H * FF, WT, H, FF);
    gemm_k<128, 128, 2, 2, 0><<<dim3(NT / 128, FF / 128), 256, 0, stream>>>(
        x, H, WT, H, gb, FF, nullptr, H);

    transpose_k<<<dim3(H / 32, FF / 32), 256, 0, stream>>>(Wu + (size_t)l * H * FF, WT, H, FF);
    gemm_k<128, 128, 2, 2, 2><<<dim3(NT / 128, FF / 128), 256, 0, stream>>>(
        x, H, WT, H, ub, FF, gb, H);

    transpose_k<<<dim3(FF / 32, H / 32), 256, 0, stream>>>(Wd + (size_t)l * FF * H, WT, FF, H);
    gemm_k<128, 128, 2, 2, 1><<<dim3(NT / 128, H / 128), 256, 0, stream>>>(
        ub, FF, WT, FF, h, H, nullptr, FF);
  }

  rmsnorm_k<<<NT, 256, 0, stream>>>(h, nw, x);
  transpose_k<<<dim3(H / 32, V / 32), 256, 0, stream>>>(lmw, WT, H, V);
  gemm_k<128, 128, 2, 2, 3><<<dim3(NT / 128, V / 128), 256, 0, stream>>>(
      x, H, WT, H, out, V, nullptr, H);
}

// Round 3
// 2581.524 us; speedup vs baseline: 1.3202x; 1.0644x over previous
//
#include <hip/hip_runtime.h>

// ---------------------------------------------------------------------------
// Qwen3-style 8-layer transformer forward on MI355X (gfx950).
// Round 3: 256x256 8-phase-style GEMM (4-slot LDS ring, counted vmcnt(8),
// XOR-swizzle, setprio, XCD block swizzle) for lm_head + fused gate|up;
// flash attention; fused QKV GEMM; table RoPE.
// ---------------------------------------------------------------------------

typedef unsigned short u16;
typedef __bf16  bf16x8 __attribute__((ext_vector_type(8)));   // 4 VGPRs
typedef unsigned short u16x8 __attribute__((ext_vector_type(8)));
typedef float   f32x4  __attribute__((ext_vector_type(4)));

#define DEV static __device__ __forceinline__

constexpr int NB  = 2;
constexpr int S   = 1024;
constexpr int NT  = NB * S;
constexpr int H   = 1024;
constexpr int NH  = 16;
constexpr int NKV = 8;
constexpr int HD  = 64;
constexpr int NL  = 8;
constexpr int FF  = 4096;
constexpr int V   = 32000;
constexpr int QKVW = 2048;

DEV float b2f(u16 x) { return __uint_as_float(((unsigned)x) << 16); }
DEV u16   f2b(float f) {
  unsigned i = __float_as_uint(f);
  return (u16)((i + 0x7fffu + ((i >> 16) & 1u)) >> 16);   // RNE
}

DEV void gload16(const void* g, void* l) {
  __builtin_amdgcn_global_load_lds(
      (const __attribute__((address_space(1))) void*)g,
      (__attribute__((address_space(3))) void*)l, 16, 0, 0);
}

DEV bf16x8 ld128(const u16* p) { return *reinterpret_cast<const bf16x8*>(p); }

// ---------------------------------------------------------------------------
// 256x256-tile GEMM, 8-phase-style schedule.  C = A[M,K] * Bt[N,K]^T.
// 512 thr = 8 waves (2Mx4N), per-wave 128x64 out, BK=32, 4-slot LDS ring
// (depth-3 prefetch, steady vmcnt(8)).  EPI: 0 = bf16 out, 3 = f32 out.
// Requires M%256==0, N%256==0, K%32==0, K/32>=4, (gridX*gridY)%8==0.
// ---------------------------------------------------------------------------
template <int EPI>
__global__ __launch_bounds__(512, 2) void gemm256_k(
    const u16* __restrict__ A, int lda,
    const u16* __restrict__ Bt, int ldb,
    void* __restrict__ C, int ldc, int K)
{
  __shared__ __align__(16) u16 Asm[4][256 * 32];   // 64 KiB
  __shared__ __align__(16) u16 Bsm[4][256 * 32];   // 64 KiB

  const int tid  = threadIdx.x;
  const int lane = tid & 63;
  const int lrow = lane & 15;
  const int g    = lane >> 4;
  const int wid  = tid >> 6;
  const int wm   = wid >> 2, wn = wid & 3;

  // XCD-aware bijective block swizzle (nwg % 8 == 0 by launch contract)
  int flat = blockIdx.y * gridDim.x + blockIdx.x;
  const int cpx = (gridDim.x * gridDim.y) >> 3;
  flat = (flat & 7) * cpx + (flat >> 3);
  const int bx = flat % gridDim.x;
  const int by = flat / gridDim.x;

  // staging: LDS chunk c = i*512+tid -> row=c>>2, slot pp=c&3 holds global
  // k-chunk p = pp ^ s(row), s(row) = (row ^ (row>>2)) & 3  (involution)
  const int r0   = tid >> 2, pp = tid & 3;
  const int row1 = 128 + (tid >> 2);
  const int p0 = pp ^ ((r0 ^ (r0 >> 2)) & 3);
  const int p1 = pp ^ ((row1 ^ (row1 >> 2)) & 3);
  const u16* aS0 = A  + (size_t)(bx * 256 + r0)   * lda + p0 * 8;
  const u16* aS1 = A  + (size_t)(bx * 256 + row1) * lda + p1 * 8;
  const u16* bS0 = Bt + (size_t)(by * 256 + r0)   * ldb + p0 * 8;
  const u16* bS1 = Bt + (size_t)(by * 256 + row1) * ldb + p1 * 8;
  const int aB0 = tid * 16, aB1 = (512 + tid) * 16;   // lds byte offsets

  int aOff[8], bOff[4];
  #pragma unroll
  for (int fm = 0; fm < 8; fm++) {
    const int r = wm * 128 + fm * 16 + lrow;
    aOff[fm] = r * 32 + (g ^ ((r ^ (r >> 2)) & 3)) * 8;
  }
  #pragma unroll
  for (int fn = 0; fn < 4; fn++) {
    const int r = wn * 64 + fn * 16 + lrow;
    bOff[fn] = r * 32 + (g ^ ((r ^ (r >> 2)) & 3)) * 8;
  }

  f32x4 acc[8][4] = {};
  const int ntk = K / 32;

  // prologue: stage tiles 0,1,2 (4 loads each, FIFO by tile)
  #pragma unroll
  for (int ts = 0; ts < 3; ts++) {
    const long kt = (long)ts * 32;
    gload16(aS0 + kt, (char*)Asm[ts] + aB0);
    gload16(bS0 + kt, (char*)Bsm[ts] + aB0);
    gload16(aS1 + kt, (char*)Asm[ts] + aB1);
    gload16(bS1 + kt, (char*)Bsm[ts] + aB1);
  }
  asm volatile("s_waitcnt vmcnt(8)" ::: "memory");
  __builtin_amdgcn_s_barrier();

#define KTILE(VMW, STG)                                                         \
  {                                                                             \
    const int rs = t & 3, ss = (t + 3) & 3;                                     \
    const long kt = (long)(t + 3) * 32;                                         \
    bf16x8 af[4], bf[4];                                                        \
    _Pragma("unroll") for (int i = 0; i < 4; i++) bf[i] = ld128(&Bsm[rs][bOff[i]]); \
    _Pragma("unroll") for (int i = 0; i < 4; i++) af[i] = ld128(&Asm[rs][aOff[i]]); \
    if (STG) { gload16(aS0 + kt, (char*)Asm[ss] + aB0);                         \
               gload16(bS0 + kt, (char*)Bsm[ss] + aB0); }                       \
    __builtin_amdgcn_s_barrier();                                               \
    asm volatile("s_waitcnt lgkmcnt(0)" ::: "memory");                          \
    __builtin_amdgcn_sched_barrier(0);                                          \
    __builtin_amdgcn_s_setprio(1);                                              \
    _Pragma("unroll") for (int m = 0; m < 4; m++)                               \
      _Pragma("unroll") for (int n = 0; n < 4; n++)                             \
        acc[m][n] = __builtin_amdgcn_mfma_f32_16x16x32_bf16(af[m], bf[n], acc[m][n], 0, 0, 0); \
    __builtin_amdgcn_s_setprio(0);                                              \
    __builtin_amdgcn_s_barrier();                                               \
    _Pragma("unroll") for (int i = 0; i < 4; i++) af[i] = ld128(&Asm[rs][aOff[4 + i]]); \
    if (STG) { gload16(aS1 + kt, (char*)Asm[ss] + aB1);                         \
               gload16(bS1 + kt, (char*)Bsm[ss] + aB1); }                       \
    __builtin_amdgcn_s_barrier();                                               \
    asm volatile("s_waitcnt lgkmcnt(0)" ::: "memory");                          \
    __builtin_amdgcn_sched_barrier(0);                                          \
    __builtin_amdgcn_s_setprio(1);                                              \
    _Pragma("unroll") for (int m = 0; m < 4; m++)                               \
      _Pragma("unroll") for (int n = 0; n < 4; n++)                             \
        acc[4 + m][n] = __builtin_amdgcn_mfma_f32_16x16x32_bf16(af[m], bf[n], acc[4 + m][n], 0, 0, 0); \
    __builtin_amdgcn_s_setprio(0);                                              \
    VMW;                                                                        \
    __builtin_amdgcn_sched_barrier(0);                                          \
    __builtin_amdgcn_s_barrier();                                               \
  }

  {
    int t = 0;
    for (; t < ntk - 3; ++t) KTILE(asm volatile("s_waitcnt vmcnt(8)" ::: "memory"), true);
    KTILE(asm volatile("s_waitcnt vmcnt(4)" ::: "memory"), false); ++t;
    KTILE(asm volatile("s_waitcnt vmcnt(0)" ::: "memory"), false); ++t;
    KTILE((void)0, false);
  }
#undef KTILE

  #pragma unroll
  for (int fm = 0; fm < 8; fm++) {
    #pragma unroll
    for (int fn = 0; fn < 4; fn++) {
      #pragma unroll
      for (int r = 0; r < 4; r++) {
        const size_t row = bx * 256 + wm * 128 + fm * 16 + g * 4 + r;
        const size_t col = by * 256 + wn * 64 + fn * 16 + lrow;
        if (EPI == 0) ((u16*)C)[row * ldc + col] = f2b(acc[fm][fn][r]);
        else          ((float*)C)[row * ldc + col] = acc[fm][fn][r];
      }
    }
  }
}

// ---------------------------------------------------------------------------
// 128x128 GEMM (m97 structure).  EPI: 0 bf16; 1 f32 residual add; 3 f32 out.
// ---------------------------------------------------------------------------
template <int BM, int BN, int WM, int WN, int EPI>
__global__ __launch_bounds__(256) void gemm_k(
    const u16* __restrict__ A, int lda,
    const u16* __restrict__ Bt, int ldb,
    void* __restrict__ C, int ldc,
    const void* __restrict__ aux, int K)
{
  __shared__ __align__(16) u16 As[BM * 32];
  __shared__ __align__(16) u16 Bs[BN * 32];

  const int tid  = threadIdx.x;
  const int lane = tid & 63;
  const int lrow = lane & 15;
  const int kb   = lane >> 4;
  const int w    = tid >> 6;
  const int wm   = w / WN, wn = w % WN;
  constexpr int WR = BM / WM, WC = BN / WN;
  constexpr int FM = WR / 16, FN = WC / 16;

  const u16* Ap = A + blockIdx.x * BM * lda;
  const u16* Bp = Bt + blockIdx.y * BN * ldb;

  f32x4 acc[FM][FN] = {};

  for (int k0 = 0; k0 < K; k0 += 32) {
    #pragma unroll
    for (int i = 0; i < (BM * 4) / 256; i++) {
      const int c = i * 256 + tid;
      gload16(Ap + (c >> 2) * lda + k0 + (c & 3) * 8, (char*)As + c * 16);
    }
    #pragma unroll
    for (int i = 0; i < (BN * 4) / 256; i++) {
      const int c = i * 256 + tid;
      gload16(Bp + (c >> 2) * ldb + k0 + (c & 3) * 8, (char*)Bs + c * 16);
    }
    __syncthreads();

    bf16x8 af[FM], bfv[FN];
    #pragma unroll
    for (int fm = 0; fm < FM; fm++)
      af[fm] = *reinterpret_cast<const bf16x8*>(As + (wm * WR + fm * 16 + lrow) * 32 + kb * 8);
    #pragma unroll
    for (int fn = 0; fn < FN; fn++)
      bfv[fn] = *reinterpret_cast<const bf16x8*>(Bs + (wn * WC + fn * 16 + lrow) * 32 + kb * 8);

    #pragma unroll
    for (int fm = 0; fm < FM; fm++) {
      #pragma unroll
      for (int fn = 0; fn < FN; fn++) {
        acc[fm][fn] = __builtin_amdgcn_mfma_f32_16x16x32_bf16(af[fm], bfv[fn], acc[fm][fn], 0, 0, 0);
      }
    }
    __syncthreads();
  }

  #pragma unroll
  for (int fm = 0; fm < FM; fm++) {
    #pragma unroll
    for (int fn = 0; fn < FN; fn++) {
      #pragma unroll
      for (int r = 0; r < 4; r++) {
        const int row = blockIdx.x * BM + wm * WR + fm * 16 + kb * 4 + r;
        const int col = blockIdx.y * BN + wn * WC + fn * 16 + lrow;
        const float vv = acc[fm][fn][r];
        if (EPI == 0) {
          ((u16*)C)[row * ldc + col] = f2b(vv);
        } else if (EPI == 1) {
          ((float*)C)[row * ldc + col] += vv;
        } else {
          ((float*)C)[(size_t)row * ldc + col] = vv;
        }
      }
    }
  }
}

// ---------------------------------------------------------------------------
__global__ __launch_bounds__(256) void transpose_k(
    const float* __restrict__ W, u16* __restrict__ WT, int K, int N)
{
  __shared__ float t[32][33];
  const int k0 = blockIdx.x * 32, n0 = blockIdx.y * 32;
  const int tx = threadIdx.x & 31, ty = threadIdx.x >> 5;
  #pragma unroll
  for (int i = 0; i < 32; i += 8)
    t[ty + i][tx] = W[(size_t)(k0 + ty + i) * N + (n0 + tx)];
  __syncthreads();
  #pragma unroll
  for (int i = 0; i < 32; i += 8)
    WT[(size_t)(n0 + ty + i) * K + (k0 + tx)] = f2b(t[tx][ty + i]);
}

// ---------------------------------------------------------------------------
__global__ __launch_bounds__(256) void embed_k(
    const int* __restrict__ ids, const float* __restrict__ E, float* __restrict__ h)
{
  const int t = blockIdx.x;
  const int id = ids[t];
  ((float4*)(h + t * H))[threadIdx.x] = ((const float4*)(E + (size_t)id * H))[threadIdx.x];
}

// ---------------------------------------------------------------------------
__global__ __launch_bounds__(256) void rmsnorm_k(
    const float* __restrict__ h, const float* __restrict__ w, u16* __restrict__ x)
{
  const int row = blockIdx.x;
  const float4 hv = ((const float4*)(h + row * H))[threadIdx.x];
  float s = hv.x * hv.x + hv.y * hv.y + hv.z * hv.z + hv.w * hv.w;
  #pragma unroll
  for (int off = 32; off; off >>= 1) s += __shfl_xor(s, off, 64);
  __shared__ float red[4];
  if ((threadIdx.x & 63) == 0) red[threadIdx.x >> 6] = s;
  __syncthreads();
  s = red[0] + red[1] + red[2] + red[3];
  const float scale = rsqrtf(s * (1.f / H) + 1e-6f);
  const float4 wv = ((const float4*)w)[threadIdx.x];
  ushort4 ov;
  ov.x = f2b(hv.x * scale * wv.x);
  ov.y = f2b(hv.y * scale * wv.y);
  ov.z = f2b(hv.z * scale * wv.z);
  ov.w = f2b(hv.w * scale * wv.w);
  ((ushort4*)(x + row * H))[threadIdx.x] = ov;
}

// ---------------------------------------------------------------------------
__global__ __launch_bounds__(256) void ropetab_k(float2* __restrict__ tab)
{
  const int idx = blockIdx.x * 256 + threadIdx.x;
  const int s = idx >> 5, d = idx & 31;
  const float ang = s * powf(10000.f, -(2.f * d) / 64.f);
  float sn, cs;
  sincosf(ang, &sn, &cs);
  tab[idx] = make_float2(cs, sn);
}

__global__ __launch_bounds__(256) void rope_k(
    u16* __restrict__ qkv, const float2* __restrict__ tab)
{
  const int idx = blockIdx.x * 256 + threadIdx.x;
  const int d = idx & 31;
  const int rest = idx >> 5;
  const int hh = rest % 24;
  const int t = rest / 24;
  const int s = t & (S - 1);
  const float2 cssn = tab[s * 32 + d];
  const float scale = (hh < 16) ? 0.125f : 1.0f;
  const int col = (hh < 16) ? hh * 64 : 1024 + (hh - 16) * 64;
  u16* p = qkv + (size_t)t * QKVW + col + d;
  const float x1 = b2f(p[0]), x2 = b2f(p[32]);
  p[0]  = f2b((x1 * cssn.x - x2 * cssn.y) * scale);
  p[32] = f2b((x2 * cssn.x + x1 * cssn.y) * scale);
}

// ---------------------------------------------------------------------------
// silu-mul: out[t][j] = silu(gu[t][j]) * gu[t][4096+j]
// ---------------------------------------------------------------------------
__global__ __launch_bounds__(256) void silu_k(
    const u16* __restrict__ gu, u16* __restrict__ out)
{
  const int idx = blockIdx.x * 256 + threadIdx.x;   // NT*512
  const int row = idx >> 9, cj = idx & 511;
  const u16x8 gv = *reinterpret_cast<const u16x8*>(gu + (size_t)row * 8192 + cj * 8);
  const u16x8 uv = *reinterpret_cast<const u16x8*>(gu + (size_t)row * 8192 + 4096 + cj * 8);
  u16x8 ov;
  #pragma unroll
  for (int j = 0; j < 8; j++) {
    const float gg = b2f(gv[j]);
    ov[j] = f2b(gg / (1.f + __expf(-gg)) * b2f(uv[j]));
  }
  *reinterpret_cast<u16x8*>(out + (size_t)row * 4096 + cj * 8) = ov;
}

// ---------------------------------------------------------------------------
// Flash attention (unchanged from round 2).
// ---------------------------------------------------------------------------
__global__ __launch_bounds__(256) void fattn_k(
    const u16* __restrict__ qkv, u16* __restrict__ o)
{
  __shared__ __align__(16) u16 Ks[64 * 64];
  __shared__ __align__(16) u16 Vt[64 * 72];
  __shared__ __align__(16) u16 Pw[4][16 * 64];

  const int tid  = threadIdx.x;
  const int lane = tid & 63;
  const int lrow = lane & 15;
  const int g    = lane >> 4;
  const int w    = tid >> 6;
  const int bx = blockIdx.x, by = blockIdx.y;
  const int b = by >> 4, hh = by & 15, kh = hh >> 1;
  const int q0 = bx * 64;

  bf16x8 aq[2];
  {
    const int qrow = q0 + w * 16 + lrow;
    const u16* qp = qkv + (size_t)(b * S + qrow) * QKVW + hh * 64 + g * 8;
    aq[0] = *reinterpret_cast<const bf16x8*>(qp);
    aq[1] = *reinterpret_cast<const bf16x8*>(qp + 32);
  }

  f32x4 oacc[4] = {};
  float mrow[4], lsum[4];
  #pragma unroll
  for (int r = 0; r < 4; r++) { mrow[r] = -1e30f; lsum[r] = 0.f; }

  const int nt = bx + 1;
  for (int t = 0; t < nt; t++) {
    const int kv0 = t * 64;
    __syncthreads();

    #pragma unroll
    for (int i = 0; i < 2; i++) {
      const int c = i * 256 + tid;
      const int r = c >> 3, p = c & 7;
      gload16(qkv + (size_t)(b * S + kv0 + r) * QKVW + 1024 + kh * 64 + ((p ^ (r & 7)) * 8),
              (char*)Ks + c * 16);
    }
    u16x8 vreg[2];
    #pragma unroll
    for (int i = 0; i < 2; i++) {
      const int c = i * 256 + tid;
      const int k = c >> 3, dch = c & 7;
      vreg[i] = *reinterpret_cast<const u16x8*>(
          qkv + (size_t)(b * S + kv0 + k) * QKVW + 1536 + kh * 64 + dch * 8);
    }
    #pragma unroll
    for (int i = 0; i < 2; i++) {
      const int c = i * 256 + tid;
      const int k = c >> 3, d0 = (c & 7) * 8;
      #pragma unroll
      for (int j = 0; j < 8; j++) {
        const int d = d0 + j;
        Vt[d * 72 + (((k >> 3) ^ (d >> 3)) * 8) + (k & 7)] = vreg[i][j];
      }
    }
    __syncthreads();

    f32x4 sacc[4] = {};
    #pragma unroll
    for (int n = 0; n < 4; n++) {
      const int row = n * 16 + lrow;
      #pragma unroll
      for (int k2 = 0; k2 < 2; k2++) {
        const bf16x8 bk = *reinterpret_cast<const bf16x8*>(
            Ks + row * 64 + (((k2 * 4 + g) ^ (row & 7)) * 8));
        sacc[n] = __builtin_amdgcn_mfma_f32_16x16x32_bf16(aq[k2], bk, sacc[n], 0, 0, 0);
      }
    }

    #pragma unroll
    for (int r = 0; r < 4; r++) {
      const int qglob = q0 + w * 16 + g * 4 + r;
      float sv[4];
      float rm = -1e30f;
      #pragma unroll
      for (int n = 0; n < 4; n++) {
        const int kg = kv0 + n * 16 + lrow;
        sv[n] = (kg <= qglob) ? sacc[n][r] : -1e30f;
        rm = fmaxf(rm, sv[n]);
      }
      #pragma unroll
      for (int mk = 1; mk < 16; mk <<= 1) rm = fmaxf(rm, __shfl_xor(rm, mk, 64));
      const float mnew  = fmaxf(mrow[r], rm);
      const float scale = __expf(mrow[r] - mnew);
      float rs = 0.f;
      u16 pb[4];
      #pragma unroll
      for (int n = 0; n < 4; n++) {
        const float p = __expf(sv[n] - mnew);
        rs += p;
        pb[n] = f2b(p);
      }
      #pragma unroll
      for (int mk = 1; mk < 16; mk <<= 1) rs += __shfl_xor(rs, mk, 64);
      lsum[r] = lsum[r] * scale + rs;
      mrow[r] = mnew;
      #pragma unroll
      for (int dt = 0; dt < 4; dt++) oacc[dt][r] *= scale;
      const int ql = g * 4 + r;
      #pragma unroll
      for (int n = 0; n < 4; n++) {
        const int k = n * 16 + lrow;
        Pw[w][ql * 64 + (((k >> 3) ^ (ql & 7)) * 8) + (k & 7)] = pb[n];
      }
    }

    #pragma unroll
    for (int k2 = 0; k2 < 2; k2++) {
      const bf16x8 pa = *reinterpret_cast<const bf16x8*>(
          &Pw[w][lrow * 64 + (((k2 * 4 + g) ^ (lrow & 7)) * 8)]);
      #pragma unroll
      for (int dt = 0; dt < 4; dt++) {
        const int d = dt * 16 + lrow;
        const bf16x8 vb = *reinterpret_cast<const bf16x8*>(
            &Vt[d * 72 + (((k2 * 4 + g) ^ (d >> 3)) * 8)]);
        oacc[dt] = __builtin_amdgcn_mfma_f32_16x16x32_bf16(pa, vb, oacc[dt], 0, 0, 0);
      }
    }
  }

  #pragma unroll
  for (int dt = 0; dt < 4; dt++) {
    #pragma unroll
    for (int r = 0; r < 4; r++) {
      const int qrow = q0 + w * 16 + g * 4 + r;
      o[(size_t)(b * S + qrow) * H + hh * 64 + dt * 16 + lrow] =
          f2b(oacc[dt][r] / lsum[r]);
    }
  }
}

// ---------------------------------------------------------------------------
extern "C" void kernel_launch(void* const* d_in, const int* in_sizes, int n_in,
                              void* d_out, int out_size, void* d_ws, size_t ws_size,
                              hipStream_t stream)
{
  const int*   ids  = (const int*)d_in[0];
  const float* EW   = (const float*)d_in[1];
  const float* Wq   = (const float*)d_in[2];
  const float* Wk   = (const float*)d_in[3];
  const float* Wv   = (const float*)d_in[4];
  const float* Wo   = (const float*)d_in[5];
  const float* Wg   = (const float*)d_in[6];
  const float* Wu   = (const float*)d_in[7];
  const float* Wd   = (const float*)d_in[8];
  const float* ln1  = (const float*)d_in[9];
  const float* ln2  = (const float*)d_in[10];
  const float* nw   = (const float*)d_in[11];
  const float* lmw  = (const float*)d_in[12];
  float* out = (float*)d_out;

  char* ws = (char*)d_ws;
  float*  h   = (float*)(ws);                     // 8 MiB  [NT][H] f32
  u16*    x   = (u16*)(ws + (8u  << 20));         // 4 MiB  [NT][H]
  u16*    qkv = (u16*)(ws + (12u << 20));         // 8 MiB  [NT][2048]
  u16*    o   = (u16*)(ws + (20u << 20));         // 4 MiB  [NT][H]
  u16*    guB = (u16*)(ws + (24u << 20));         // 32 MiB [NT][8192]
  u16*    ub  = (u16*)(ws + (56u << 20));         // 16 MiB [NT][4096]
  u16*    WT  = (u16*)(ws + (72u << 20));         // 62.5 MiB (max lm_head)
  float2* tab = (float2*)(ws + (136u << 20));     // 256 KiB [S][32]

  const size_t needed = (137u << 20);
  if (ws_size < needed) return;

  embed_k<<<NT, 256, 0, stream>>>(ids, EW, h);
  ropetab_k<<<(S * 32) / 256, 256, 0, stream>>>(tab);

  for (int l = 0; l < NL; l++) {
    // ---- attention ----
    rmsnorm_k<<<NT, 256, 0, stream>>>(h, ln1 + l * H, x);

    transpose_k<<<dim3(H / 32, H / 32), 256, 0, stream>>>(Wq + (size_t)l * H * H, WT, H, H);
    transpose_k<<<dim3(H / 32, 512 / 32), 256, 0, stream>>>(Wk + (size_t)l * H * 512, WT + 1024 * H, H, 512);
    transpose_k<<<dim3(H / 32, 512 / 32), 256, 0, stream>>>(Wv + (size_t)l * H * 512, WT + 1536 * H, H, 512);
    gemm_k<128, 128, 2, 2, 0><<<dim3(NT / 128, QKVW / 128), 256, 0, stream>>>(
        x, H, WT, H, qkv, QKVW, nullptr, H);

    rope_k<<<(NT * 24 * 32) / 256, 256, 0, stream>>>(qkv, tab);

    fattn_k<<<dim3(S / 64, NB * NH), 256, 0, stream>>>(qkv, o);

    transpose_k<<<dim3(H / 32, H / 32), 256, 0, stream>>>(Wo + (size_t)l * H * H, WT, H, H);
    gemm_k<128, 128, 2, 2, 1><<<dim3(NT / 128, H / 128), 256, 0, stream>>>(
        o, H, WT, H, h, H, nullptr, H);

    // ---- MLP ----
    rmsnorm_k<<<NT, 256, 0, stream>>>(h, ln2 + l * H, x);

    transpose_k<<<dim3(H / 32, FF / 32), 256, 0, stream>>>(Wg + (size_t)l * H * FF, WT, H, FF);
    transpose_k<<<dim3(H / 32, FF / 32), 256, 0, stream>>>(Wu + (size_t)l * H * FF, WT + (size_t)FF * H, H, FF);
    gemm256_k<0><<<dim3(NT / 256, (2 * FF) / 256), 512, 0, stream>>>(
        x, H, WT, H, guB, 2 * FF, H);

    silu_k<<<(NT * 512) / 256, 256, 0, stream>>>(guB, ub);

    transpose_k<<<dim3(FF / 32, H / 32), 256, 0, stream>>>(Wd + (size_t)l * FF * H, WT, FF, H);
    gemm_k<128, 128, 2, 2, 1><<<dim3(NT / 128, H / 128), 256, 0, stream>>>(
        ub, FF, WT, FF, h, H, nullptr, FF);
  }

  rmsnorm_k<<<NT, 256, 0, stream>>>(h, nw, x);
  transpose_k<<<dim3(H / 32, V / 32), 256, 0, stream>>>(lmw, WT, H, V);
  gemm256_k<3><<<dim3(NT / 256, V / 256), 512, 0, stream>>>(
      x, H, WT, H, out, V, H);
}